// Round 3
// baseline (195.967 us; speedup 1.0000x reference)
//
#include <hip/hip_runtime.h>
#include <hip/hip_bf16.h>
#include <stdint.h>

typedef __bf16 bf16_t;
typedef __bf16 bf16x4 __attribute__((ext_vector_type(4)));
typedef __bf16 bf16x8 __attribute__((ext_vector_type(8)));
typedef float  f32x4  __attribute__((ext_vector_type(4)));

// ---- workspace layout (bytes) ----
static constexpr size_t WT_OFF = 0;                    // Wt bf16 [384][1024] = 768 KB
static constexpr size_t Q_OFF  = (size_t)1 << 20;      // q bf16 [16384][128] = 4 MB
static constexpr size_t K_OFF  = Q_OFF + ((size_t)4 << 20);
static constexpr size_t VT_OFF = K_OFF + ((size_t)4 << 20);  // vT bf16 [8][128][2048] = 4 MB

// ---------------- W transpose: W[1024][128] fp32 -> Wt[384][1024] bf16 ----------------
__global__ __launch_bounds__(256) void wt_kernel(const float* __restrict__ Wq,
                                                 const float* __restrict__ Wk,
                                                 const float* __restrict__ Wv,
                                                 bf16_t* __restrict__ wt) {
  __shared__ float tile[64][129];
  int wi = blockIdx.x >> 4;   // 0..2
  int ct = blockIdx.x & 15;   // 0..15 -> c0
  const float* W = (wi == 0) ? Wq : ((wi == 1) ? Wk : Wv);
  int c0 = ct * 64;
  int tid = threadIdx.x;
  for (int i = 0; i < 32; ++i) {
    int idx = i * 256 + tid;
    int c = idx >> 7, n = idx & 127;
    tile[c][n] = W[(size_t)(c0 + c) * 128 + n];   // coalesced read
  }
  __syncthreads();
  for (int i = 0; i < 32; ++i) {
    int idx = i * 256 + tid;
    int n = idx >> 6, c = idx & 63;
    wt[(size_t)(wi * 128 + n) * 1024 + c0 + c] = (bf16_t)tile[c][n];  // coalesced-ish write
  }
}

// ---------------- fused QKV projection v3: 4x4 register-blocked --------------------
// Grid 768 = 3 slices x 256 t-tiles(64), XCD-chunked (96/XCD, 3 slices of a t-tile
// co-resident on one XCD -> x L2-shared). Block 128 thr = 2 waves (n-halves).
// Wave tile: n=64 (4 A-frags) x t=64 (4 B-frags) -> 16 MFMA / 12 loads per k-step.
__global__ __launch_bounds__(128, 3) void proj_kernel(const float* __restrict__ x,
                                                      const bf16_t* __restrict__ wt,
                                                      bf16_t* __restrict__ q,
                                                      bf16_t* __restrict__ k,
                                                      bf16_t* __restrict__ vT) {
  int wgid = (blockIdx.x & 7) * 96 + (blockIdx.x >> 3);
  int t_tile = wgid / 3;
  int slice = wgid % 3;          // 0=Q, 1=K, 2=V
  int n0 = slice * 128;

  int lane = threadIdx.x & 63;
  int wave = threadIdx.x >> 6;   // n-half
  int lq = lane & 15, grp = lane >> 4;
  int t0 = t_tile * 64;

  f32x4 acc[4][4];
#pragma unroll
  for (int a = 0; a < 4; ++a)
#pragma unroll
    for (int bq = 0; bq < 4; ++bq) acc[a][bq] = (f32x4){0.f, 0.f, 0.f, 0.f};

  const bf16_t* wbase = wt + (size_t)(n0 + wave * 64 + lq) * 1024 + grp * 8;
  const float*  xbase = x + (size_t)(t0 + lq) * 1024 + grp * 8;

  float4 xp[4][2];
#pragma unroll
  for (int bq = 0; bq < 4; ++bq) {
    xp[bq][0] = *(const float4*)(xbase + (size_t)(bq * 16) * 1024);
    xp[bq][1] = *(const float4*)(xbase + (size_t)(bq * 16) * 1024 + 4);
  }

  for (int ks = 0; ks < 32; ++ks) {
    int k0 = ks * 32;
    bf16x8 xf[4];
#pragma unroll
    for (int bq = 0; bq < 4; ++bq) {
      xf[bq][0] = (bf16_t)xp[bq][0].x; xf[bq][1] = (bf16_t)xp[bq][0].y;
      xf[bq][2] = (bf16_t)xp[bq][0].z; xf[bq][3] = (bf16_t)xp[bq][0].w;
      xf[bq][4] = (bf16_t)xp[bq][1].x; xf[bq][5] = (bf16_t)xp[bq][1].y;
      xf[bq][6] = (bf16_t)xp[bq][1].z; xf[bq][7] = (bf16_t)xp[bq][1].w;
    }
    int kn = ((ks + 1) & 31) * 32;   // prefetch next step (wraps harmlessly)
#pragma unroll
    for (int bq = 0; bq < 4; ++bq) {
      xp[bq][0] = *(const float4*)(xbase + (size_t)(bq * 16) * 1024 + kn);
      xp[bq][1] = *(const float4*)(xbase + (size_t)(bq * 16) * 1024 + kn + 4);
    }
    bf16x8 wf[4];
#pragma unroll
    for (int a = 0; a < 4; ++a)
      wf[a] = *(const bf16x8*)(wbase + (size_t)(a * 16) * 1024 + k0);
#pragma unroll
    for (int a = 0; a < 4; ++a)
#pragma unroll
      for (int bq = 0; bq < 4; ++bq)
        acc[a][bq] = __builtin_amdgcn_mfma_f32_16x16x32_bf16(wf[a], xf[bq], acc[a][bq], 0, 0, 0);
  }

  if (slice < 2) {   // Q or K row-major: rows t, cols n
    bf16_t* dst = (slice == 0) ? q : k;
#pragma unroll
    for (int a = 0; a < 4; ++a)
#pragma unroll
      for (int bq = 0; bq < 4; ++bq) {
        bf16x4 o;
        o[0] = (bf16_t)acc[a][bq][0]; o[1] = (bf16_t)acc[a][bq][1];
        o[2] = (bf16_t)acc[a][bq][2]; o[3] = (bf16_t)acc[a][bq][3];
        *(bf16x4*)(dst + (size_t)(t0 + bq * 16 + lq) * 128 + wave * 64 + a * 16 + grp * 4) = o;
      }
  } else {           // V transposed: vT[b][d][t]
    int b = t0 >> 11;
#pragma unroll
    for (int a = 0; a < 4; ++a)
#pragma unroll
      for (int bq = 0; bq < 4; ++bq) {
        int tt = (t0 + bq * 16 + lq) & 2047;
#pragma unroll
        for (int r = 0; r < 4; ++r) {
          int d = wave * 64 + a * 16 + grp * 4 + r;
          vT[(size_t)b * 128 * 2048 + (size_t)d * 2048 + tt] = (bf16_t)acc[a][bq][r];
        }
      }
  }
}

// ---------------- flash attention v3: 1-wave blocks, no LDS staging, no barriers ----
// 1024 blocks = 8 b x 128 q-tiles(16 rows), heavy tiles first (dynamic balance).
// K/V frags loaded straight from global (L2-resident, b aligned to XCD).
__global__ __launch_bounds__(64, 2) void attn_kernel(const bf16_t* __restrict__ q,
                                                     const bf16_t* __restrict__ k,
                                                     const bf16_t* __restrict__ vT,
                                                     float* __restrict__ out) {
  __shared__ __align__(16) char Plds[2048];   // single-wave P^T repack (no barrier needed)

  int rank = blockIdx.x >> 3;       // 0..127
  int b = blockIdx.x & 7;           // XCD-aligned batch
  int tq16 = 127 - rank;            // heavy (long prefix) first
  int lane = threadIdx.x;
  int lq = lane & 15, grp = lane >> 4;
  int tq = tq16 * 16 + lq;

  bf16x8 qf[4];
  const bf16_t* qrow = q + ((size_t)b * 2048 + tq) * 128 + grp * 8;
#pragma unroll
  for (int ks = 0; ks < 4; ++ks) qf[ks] = *(const bf16x8*)(qrow + ks * 32);

  float mrun = -__builtin_inff();
  float lsum = 0.f;
  f32x4 accO[8];
#pragma unroll
  for (int i = 0; i < 8; ++i) accO[i] = (f32x4){0.f, 0.f, 0.f, 0.f};

  const float scale = 1.0f / 32.0f;
  const bf16_t* kbase = k + (size_t)b * 2048 * 128;
  const bf16_t* vbase = vT + (size_t)b * 128 * 2048;

  int ntiles = (tq16 >> 2) + 1;
  for (int it = 0; it < ntiles; ++it) {
    int kv0 = it * 64;

    // S^T = K · Q^T : K frags direct from global
    f32x4 s[4];
#pragma unroll
    for (int i = 0; i < 4; ++i) s[i] = (f32x4){0.f, 0.f, 0.f, 0.f};
#pragma unroll
    for (int ks = 0; ks < 4; ++ks) {
#pragma unroll
      for (int mf = 0; mf < 4; ++mf) {
        bf16x8 kf = *(const bf16x8*)(kbase + (size_t)(kv0 + mf * 16 + lq) * 128 + ks * 32 + grp * 8);
        s[mf] = __builtin_amdgcn_mfma_f32_16x16x32_bf16(kf, qf[ks], s[mf], 0, 0, 0);
      }
    }

    // online softmax; lane owns q-row tq, holds 16 kv values
    float z[4][4];
    float pmax = -__builtin_inff();
#pragma unroll
    for (int f = 0; f < 4; ++f) {
#pragma unroll
      for (int r = 0; r < 4; ++r) {
        int kv = kv0 + f * 16 + grp * 4 + r;
        float zz = s[f][r] * scale;
        zz = (kv <= tq) ? zz : -__builtin_inff();
        z[f][r] = zz;
        pmax = fmaxf(pmax, zz);
      }
    }
    pmax = fmaxf(pmax, __shfl_xor(pmax, 16, 64));
    pmax = fmaxf(pmax, __shfl_xor(pmax, 32, 64));
    float mnew = fmaxf(mrun, pmax);
    float corr = __expf(mrun - mnew);
    float p[4][4];
    float psum = 0.f;
#pragma unroll
    for (int f = 0; f < 4; ++f) {
#pragma unroll
      for (int r = 0; r < 4; ++r) {
        p[f][r] = __expf(z[f][r] - mnew);
        psum += p[f][r];
      }
    }
    psum += __shfl_xor(psum, 16, 64);
    psum += __shfl_xor(psum, 32, 64);
    lsum = lsum * corr + psum;
    mrun = mnew;
#pragma unroll
    for (int i = 0; i < 8; ++i) accO[i] *= corr;

    // pack P^T via wave-private LDS (intra-wave: compiler orders via lgkmcnt)
#pragma unroll
    for (int f = 0; f < 4; ++f) {
      bf16x4 pw;
      pw[0] = (bf16_t)p[f][0]; pw[1] = (bf16_t)p[f][1];
      pw[2] = (bf16_t)p[f][2]; pw[3] = (bf16_t)p[f][3];
      *(bf16x4*)(Plds + ((f * 2 + (grp >> 1)) << 8) + lq * 16 + ((grp & 1) << 3)) = pw;
    }

    // O^T += V^T · P^T : V frags direct from global
#pragma unroll
    for (int kc = 0; kc < 2; ++kc) {
      bf16x8 pf = *(const bf16x8*)(Plds + ((kc * 4 + grp) << 8) + lq * 16);
#pragma unroll
      for (int mf = 0; mf < 8; ++mf) {
        bf16x8 vf = *(const bf16x8*)(vbase + (size_t)(mf * 16 + lq) * 2048 + kv0 + kc * 32 + grp * 8);
        accO[mf] = __builtin_amdgcn_mfma_f32_16x16x32_bf16(vf, pf, accO[mf], 0, 0, 0);
      }
    }
  }

  // epilogue: out[b][tq][d]
  float inv = 1.0f / lsum;
  float* orow = out + ((size_t)b * 2048 + tq) * 128;
#pragma unroll
  for (int mf = 0; mf < 8; ++mf) {
    f32x4 o;
    o[0] = accO[mf][0] * inv; o[1] = accO[mf][1] * inv;
    o[2] = accO[mf][2] * inv; o[3] = accO[mf][3] * inv;
    *(f32x4*)(orow + mf * 16 + grp * 4) = o;
  }
}

extern "C" void kernel_launch(void* const* d_in, const int* in_sizes, int n_in,
                              void* d_out, int out_size, void* d_ws, size_t ws_size,
                              hipStream_t stream) {
  const float* x  = (const float*)d_in[0];
  const float* Wq = (const float*)d_in[1];
  const float* Wk = (const float*)d_in[2];
  const float* Wv = (const float*)d_in[3];
  float* out = (float*)d_out;
  char* ws = (char*)d_ws;

  bf16_t* wt = (bf16_t*)(ws + WT_OFF);
  bf16_t* qb = (bf16_t*)(ws + Q_OFF);
  bf16_t* kb = (bf16_t*)(ws + K_OFF);
  bf16_t* vT = (bf16_t*)(ws + VT_OFF);

  hipLaunchKernelGGL(wt_kernel, dim3(48), dim3(256), 0, stream, Wq, Wk, Wv, wt);
  hipLaunchKernelGGL(proj_kernel, dim3(768), dim3(128), 0, stream, x, wt, qb, kb, vT);
  hipLaunchKernelGGL(attn_kernel, dim3(1024), dim3(64), 0, stream, qb, kb, vT, out);
}

// Round 5
// 92.487 us; speedup vs baseline: 2.1189x; 2.1189x over previous
//
#include <hip/hip_runtime.h>
#include <hip/hip_bf16.h>
#include <stdint.h>

typedef __bf16 bf16_t;
typedef __bf16 bf16x4 __attribute__((ext_vector_type(4)));
typedef __bf16 bf16x8 __attribute__((ext_vector_type(8)));
typedef float  f32x4  __attribute__((ext_vector_type(4)));

// ---- workspace layout (bytes) ----
static constexpr size_t WT_OFF = 0;                    // Wt bf16 [384][1024] = 768 KB
static constexpr size_t Q_OFF  = (size_t)1 << 20;      // q bf16 [16384][128] = 4 MB
static constexpr size_t K_OFF  = Q_OFF + ((size_t)4 << 20);
static constexpr size_t VT_OFF = K_OFF + ((size_t)4 << 20);  // vT bf16 [8][128][2048] = 4 MB

__device__ __forceinline__ void g2lds16(const void* g, void* l) {
  __builtin_amdgcn_global_load_lds(
      (__attribute__((address_space(1))) void*)(g),
      (__attribute__((address_space(3))) void*)(l), 16, 0, 0);
}

// ---------------- W transpose: W[1024][128] fp32 -> Wt[384][1024] bf16 ----------------
__global__ __launch_bounds__(256) void wt_kernel(const float* __restrict__ Wq,
                                                 const float* __restrict__ Wk,
                                                 const float* __restrict__ Wv,
                                                 bf16_t* __restrict__ wt) {
  __shared__ float tile[64][129];
  int wi = blockIdx.x >> 4;   // 0..2
  int ct = blockIdx.x & 15;   // 0..15 -> c0
  const float* W = (wi == 0) ? Wq : ((wi == 1) ? Wk : Wv);
  int c0 = ct * 64;
  int tid = threadIdx.x;
  for (int i = 0; i < 32; ++i) {
    int idx = i * 256 + tid;
    int c = idx >> 7, n = idx & 127;
    tile[c][n] = W[(size_t)(c0 + c) * 128 + n];   // coalesced read
  }
  __syncthreads();
  for (int i = 0; i < 32; ++i) {
    int idx = i * 256 + tid;
    int n = idx >> 6, c = idx & 63;
    wt[(size_t)(wi * 128 + n) * 1024 + c0 + c] = (bf16_t)tile[c][n];  // coalesced-ish write
  }
}

// ---------------- fused QKV projection v5: LDS-staged x, dbuf, 2-phase pipeline ----
// Grid 768 = 3 slices x 256 t-tiles(64), XCD-chunked. Block 128 thr = 2 waves (n-halves
// of the 128-wide slice). Per BK=64 step: stage next x-tile (8 gload_lds), 8 wt loads
// (direct L2), 16 ds_read_b128 + cvt, 32 MFMA, one barrier.
__global__ __launch_bounds__(128) void proj_kernel(const float* __restrict__ x,
                                                   const bf16_t* __restrict__ wt,
                                                   bf16_t* __restrict__ q,
                                                   bf16_t* __restrict__ k,
                                                   bf16_t* __restrict__ vT) {
  __shared__ __align__(16) char Blds[2][16384];  // x tile [64 t][64 k] f32, 16B-chunk XOR swz

  int wgid = (blockIdx.x & 7) * 96 + (blockIdx.x >> 3);
  int t_tile = wgid / 3;
  int slice = wgid % 3;          // 0=Q, 1=K, 2=V
  int n0 = slice * 128;
  int t0 = t_tile * 64;

  int tid = threadIdx.x;
  int lane = tid & 63;
  int wave = tid >> 6;           // n-half
  int lq = lane & 15, grp = lane >> 4;

  const char* xb = (const char*)x;   // global row stride 4096 B

  f32x4 acc[4][4];
#pragma unroll
  for (int a = 0; a < 4; ++a)
#pragma unroll
    for (int s = 0; s < 4; ++s) acc[a][s] = (f32x4){0.f, 0.f, 0.f, 0.f};

  const bf16_t* wbase = wt + (size_t)(n0 + wave * 64 + lq) * 1024 + grp * 8;

  // stage x tile [64][64] f32 into Blds[bi]; LDS linear, source pre-swizzled (rule 21)
  auto stageB = [&](int bi, int k0) {
#pragma unroll
    for (int i = 0; i < 8; ++i) {
      int off = i * 2048 + tid * 16;
      int row = off >> 8;              // 0..63
      int c = (off >> 4) & 15;         // 16B chunk in row
      const char* src = xb + (size_t)(t0 + row) * 4096 + (size_t)k0 * 4
                        + ((c ^ (row & 15)) << 4);
      g2lds16(src, &Blds[bi][off]);
    }
  };

  stageB(0, 0);
  __syncthreads();

  for (int ks = 0; ks < 16; ++ks) {
    int cur = ks & 1;
    if (ks < 15) stageB(cur ^ 1, (ks + 1) * 64);
    int k0 = ks * 64;

    bf16x8 wf[4][2];
#pragma unroll
    for (int kh = 0; kh < 2; ++kh)
#pragma unroll
      for (int a = 0; a < 4; ++a)
        wf[a][kh] = *(const bf16x8*)(wbase + (size_t)(a * 16) * 1024 + k0 + kh * 32);

    bf16x8 xf[4][2];
#pragma unroll
    for (int sub = 0; sub < 4; ++sub) {
      int row = sub * 16 + lq;
#pragma unroll
      for (int kh = 0; kh < 2; ++kh) {
        int c0 = kh * 8 + grp * 2;
        float4 f0 = *(const float4*)(&Blds[cur][row * 256 + (((c0)     ^ (row & 15)) << 4)]);
        float4 f1 = *(const float4*)(&Blds[cur][row * 256 + (((c0 + 1) ^ (row & 15)) << 4)]);
        bf16x8 v;
        v[0] = (bf16_t)f0.x; v[1] = (bf16_t)f0.y; v[2] = (bf16_t)f0.z; v[3] = (bf16_t)f0.w;
        v[4] = (bf16_t)f1.x; v[5] = (bf16_t)f1.y; v[6] = (bf16_t)f1.z; v[7] = (bf16_t)f1.w;
        xf[sub][kh] = v;
      }
    }

#pragma unroll
    for (int kh = 0; kh < 2; ++kh)
#pragma unroll
      for (int a = 0; a < 4; ++a)
#pragma unroll
        for (int sub = 0; sub < 4; ++sub)
          acc[a][sub] = __builtin_amdgcn_mfma_f32_16x16x32_bf16(wf[a][kh], xf[sub][kh],
                                                                acc[a][sub], 0, 0, 0);
    __syncthreads();   // drains next-stage vmcnt; protects buffer swap
  }

  if (slice < 2) {   // Q or K row-major: [t][128]
    bf16_t* dst = (slice == 0) ? q : k;
#pragma unroll
    for (int a = 0; a < 4; ++a)
#pragma unroll
      for (int sub = 0; sub < 4; ++sub) {
        bf16x4 o;
        o[0] = (bf16_t)acc[a][sub][0]; o[1] = (bf16_t)acc[a][sub][1];
        o[2] = (bf16_t)acc[a][sub][2]; o[3] = (bf16_t)acc[a][sub][3];
        *(bf16x4*)(dst + (size_t)(t0 + sub * 16 + lq) * 128 + wave * 64 + a * 16 + grp * 4) = o;
      }
  } else {           // V transposed: vT[b][d][t]
    int b = t0 >> 11;
#pragma unroll
    for (int a = 0; a < 4; ++a)
#pragma unroll
      for (int sub = 0; sub < 4; ++sub) {
        int tt = (t0 + sub * 16 + lq) & 2047;
#pragma unroll
        for (int r = 0; r < 4; ++r) {
          int d = wave * 64 + a * 16 + grp * 4 + r;
          vT[(size_t)b * 128 * 2048 + (size_t)d * 2048 + tt] = (bf16_t)acc[a][sub][r];
        }
      }
  }
}

// ---------------- flash attention v5: dbuf-K prefetch + JIT V staging ---------------
// 512 blocks = 8 b (XCD-pinned) x 64 q-tiles(32 rows), heavy-first. 128 thr = 2 waves.
// Per kv-tile: [stage K(t+1), stage V(t)] -> QK+softmax+pack -> barrier -> PV -> barrier.
__global__ __launch_bounds__(128) void attn_kernel(const bf16_t* __restrict__ q,
                                                   const bf16_t* __restrict__ k,
                                                   const bf16_t* __restrict__ vT,
                                                   float* __restrict__ out) {
  __shared__ __align__(16) char lds[53248];  // K dbuf 32K + V 16K + P 4K

  int tid = threadIdx.x;
  int lane = tid & 63;
  int wave = tid >> 6;
  int lq = lane & 15, grp = lane >> 4;
  int b = blockIdx.x & 7;            // XCD-pinned batch
  int qt = 63 - (blockIdx.x >> 3);   // heavy tiles first
  int tq = qt * 32 + wave * 16 + lq;

  bf16x8 qf[4];
  const bf16_t* qrow = q + ((size_t)b * 2048 + tq) * 128 + grp * 8;
#pragma unroll
  for (int ks = 0; ks < 4; ++ks) qf[ks] = *(const bf16x8*)(qrow + ks * 32);

  float mrun = -__builtin_inff();
  float lsum = 0.f;
  f32x4 accO[8];
#pragma unroll
  for (int i = 0; i < 8; ++i) accO[i] = (f32x4){0.f, 0.f, 0.f, 0.f};

  const float scale = 1.0f / 32.0f;
  const char* kbase = (const char*)(k + (size_t)b * 2048 * 128);
  const char* vbase = (const char*)(vT + (size_t)b * 128 * 2048);

  auto stageK = [&](int bi, int kv0) {
#pragma unroll
    for (int i = 0; i < 8; ++i) {
      int off = i * 2048 + tid * 16;
      int row = off >> 8;            // 0..63
      int c = (off >> 4) & 15;
      const char* src = kbase + (size_t)(kv0 + row) * 256 + ((c ^ (row & 7)) << 4);
      g2lds16(src, &lds[bi * 16384 + off]);
    }
  };
  auto stageV = [&](int kv0) {
#pragma unroll
    for (int i = 0; i < 8; ++i) {
      int off = i * 2048 + tid * 16;
      int row = off >> 7;            // 0..127 (d)
      int c = (off >> 4) & 7;
      const char* src = vbase + (size_t)row * 4096 + (size_t)kv0 * 2 + ((c ^ (row & 7)) << 4);
      g2lds16(src, &lds[32768 + off]);
    }
  };

  int nt = (qt * 32 + 31) / 64 + 1;
  stageK(0, 0);
  __syncthreads();

  for (int it = 0; it < nt; ++it) {
    int kv0 = it * 64;
    int cur = it & 1;
    if (it + 1 < nt) stageK(cur ^ 1, kv0 + 64);
    stageV(kv0);

    // S^T = K · Q^T from current K buffer (ready since previous barrier)
    f32x4 s[4];
#pragma unroll
    for (int i = 0; i < 4; ++i) s[i] = (f32x4){0.f, 0.f, 0.f, 0.f};
#pragma unroll
    for (int ks = 0; ks < 4; ++ks) {
#pragma unroll
      for (int mf = 0; mf < 4; ++mf) {
        int row = mf * 16 + lq;
        bf16x8 kf = *(const bf16x8*)(&lds[cur * 16384 + row * 256 + (((ks * 4 + grp) ^ (row & 7)) << 4)]);
        s[mf] = __builtin_amdgcn_mfma_f32_16x16x32_bf16(kf, qf[ks], s[mf], 0, 0, 0);
      }
    }

    // online softmax; lane owns q-row tq
    float z[4][4];
    float pmax = -__builtin_inff();
#pragma unroll
    for (int f = 0; f < 4; ++f) {
#pragma unroll
      for (int r = 0; r < 4; ++r) {
        int kv = kv0 + f * 16 + grp * 4 + r;
        float zz = s[f][r] * scale;
        zz = (kv <= tq) ? zz : -__builtin_inff();
        z[f][r] = zz;
        pmax = fmaxf(pmax, zz);
      }
    }
    pmax = fmaxf(pmax, __shfl_xor(pmax, 16, 64));
    pmax = fmaxf(pmax, __shfl_xor(pmax, 32, 64));
    float mnew = fmaxf(mrun, pmax);
    float corr = __expf(mrun - mnew);
    float p[4][4];
    float psum = 0.f;
#pragma unroll
    for (int f = 0; f < 4; ++f) {
#pragma unroll
      for (int r = 0; r < 4; ++r) {
        p[f][r] = __expf(z[f][r] - mnew);
        psum += p[f][r];
      }
    }
    psum += __shfl_xor(psum, 16, 64);
    psum += __shfl_xor(psum, 32, 64);
    lsum = lsum * corr + psum;
    mrun = mnew;
#pragma unroll
    for (int i = 0; i < 8; ++i) accO[i] *= corr;

    // pack P^T (wave-private region)
#pragma unroll
    for (int f = 0; f < 4; ++f) {
      bf16x4 pw;
      pw[0] = (bf16_t)p[f][0]; pw[1] = (bf16_t)p[f][1];
      pw[2] = (bf16_t)p[f][2]; pw[3] = (bf16_t)p[f][3];
      *(bf16x4*)(&lds[49152 + wave * 2048 + ((f * 2 + (grp >> 1)) << 8) + lq * 16 + ((grp & 1) << 3)]) = pw;
    }

    __syncthreads();   // C: drains K(t+1) + V(t) stages; V ready for PV

    // O^T += V^T · P^T
#pragma unroll
    for (int kc = 0; kc < 2; ++kc) {
      bf16x8 pf = *(const bf16x8*)(&lds[49152 + wave * 2048 + ((kc * 4 + grp) << 8) + lq * 16]);
#pragma unroll
      for (int mf = 0; mf < 8; ++mf) {
        int row = mf * 16 + lq;
        bf16x8 vf = *(const bf16x8*)(&lds[32768 + row * 128 + (((kc * 4 + grp) ^ (row & 7)) << 4)]);
        accO[mf] = __builtin_amdgcn_mfma_f32_16x16x32_bf16(vf, pf, accO[mf], 0, 0, 0);
      }
    }
    __syncthreads();   // E: all waves done with V buffer before next JIT stage
  }

  float inv = 1.0f / lsum;
  float* orow = out + ((size_t)b * 2048 + tq) * 128;
#pragma unroll
  for (int mf = 0; mf < 8; ++mf) {
    f32x4 o;
    o[0] = accO[mf][0] * inv; o[1] = accO[mf][1] * inv;
    o[2] = accO[mf][2] * inv; o[3] = accO[mf][3] * inv;
    *(f32x4*)(orow + mf * 16 + grp * 4) = o;
  }
}

extern "C" void kernel_launch(void* const* d_in, const int* in_sizes, int n_in,
                              void* d_out, int out_size, void* d_ws, size_t ws_size,
                              hipStream_t stream) {
  const float* x  = (const float*)d_in[0];
  const float* Wq = (const float*)d_in[1];
  const float* Wk = (const float*)d_in[2];
  const float* Wv = (const float*)d_in[3];
  float* out = (float*)d_out;
  char* ws = (char*)d_ws;

  bf16_t* wt = (bf16_t*)(ws + WT_OFF);
  bf16_t* qb = (bf16_t*)(ws + Q_OFF);
  bf16_t* kb = (bf16_t*)(ws + K_OFF);
  bf16_t* vT = (bf16_t*)(ws + VT_OFF);

  hipLaunchKernelGGL(wt_kernel, dim3(48), dim3(256), 0, stream, Wq, Wk, Wv, wt);
  hipLaunchKernelGGL(proj_kernel, dim3(768), dim3(128), 0, stream, x, wt, qb, kb, vT);
  hipLaunchKernelGGL(attn_kernel, dim3(512), dim3(128), 0, stream, qb, kb, vT, out);
}